// Round 4
// baseline (89.069 us; speedup 1.0000x reference)
//
#include <hip/hip_runtime.h>

constexpr int D_  = 1024;  // embedding dim
constexpr int E_  = 64;    // experts
constexpr int N_  = 1024;  // B*S tokens
constexpr int TG  = 32;    // tokens per pass (>= typical max bucket)
constexpr int CS  = 16;    // column slices (blocks per expert)
constexpr int CPB = D_ / CS;   // 64 cols per block
constexpr int KG  = 8;     // k-groups within block (tid>>5)
constexpr int KR  = D_ / KG;   // 128 k-rows per group
constexpr int DC  = 16;    // w-panel rows held in registers per chunk
constexpr int NC  = KR / DC;   // 8 chunks

// One block = (col-slice cs, expert e). 256 threads = 8 k-groups x 32 col-threads.
// Per chunk: hoist 16 w-rows (float2/lane) into registers -- 8 KB/wave in flight,
// latency drains under the staging barriers; compute phase is stall-free
// (registers + LDS broadcast reads only). trans streamed from HBM exactly once.
__global__ __launch_bounds__(256, 4) void fused_moe_kernel(
    const float* __restrict__ x, const int* __restrict__ urls,
    const float* __restrict__ trans, const float* __restrict__ bias,
    float* __restrict__ out) {
  __shared__ __align__(16) float xs[KG][TG][DC];  // 16 KB
  __shared__ float2 red[KG][TG][9];               // 18 KB (pad 9: conflict-free)
  __shared__ int toksL[N_];                       // 4 KB
  __shared__ int cntS;

  const int tid = threadIdx.x;
  const int cs  = blockIdx.x;
  const int e   = blockIdx.y;
  const int kg  = tid >> 5;   // 0..7
  const int ct  = tid & 31;   // 0..31
  const int c0  = cs * CPB;

  // ---- in-block bucketing: list of tokens routed to expert e ----
  if (tid == 0) cntS = 0;
  __syncthreads();
  for (int i = tid; i < N_; i += 256) {
    if (urls[i] == e) { int p = atomicAdd(&cntS, 1); toksL[p] = i; }
  }
  __syncthreads();
  const int Ttot = cntS;

  const float* __restrict__ tr = trans + (size_t)e * D_ * D_ + c0;

  for (int beg = 0; beg < Ttot; beg += TG) {
    const int T    = (Ttot - beg < TG) ? (Ttot - beg) : TG;
    const int nOct = (T + 7) >> 3;

    float2 acc[TG];
#pragma unroll
    for (int t = 0; t < TG; ++t) acc[t] = make_float2(0.f, 0.f);

    for (int c = 0; c < NC; ++c) {
      // issue the whole w-panel for this chunk; latency hides under the
      // barrier wait + x staging below (drained by the 2nd __syncthreads)
      float2 w[DC];
#pragma unroll
      for (int r = 0; r < DC; ++r)
        w[r] = *(const float2*)&tr[(size_t)(kg * KR + c * DC + r) * D_ + ct * 2];

      __syncthreads();  // xs free (prev compute reads done)
      // stage: KG*TG*DC floats = 1024 float4 -> 4 per thread
#pragma unroll
      for (int it = 0; it < 4; ++it) {
        const int i  = tid + it * 256;
        const int j4 = i & 3;           // float4 within row (DC/4 = 4)
        const int t  = (i >> 2) & 31;   // token slot
        const int g  = i >> 7;          // k-group
        float4 v = make_float4(0.f, 0.f, 0.f, 0.f);
        if (t < T)
          v = *(const float4*)&x[(size_t)toksL[beg + t] * D_ + g * KR + c * DC + j4 * 4];
        *(float4*)&xs[g][t][j4 * 4] = v;
      }
      __syncthreads();

      // stall-free compute: w in regs, xs via LDS broadcast
#pragma unroll
      for (int dd4 = 0; dd4 < DC / 4; ++dd4) {
#pragma unroll
        for (int oct = 0; oct < TG / 8; ++oct) {
          if (oct < nOct) {  // uniform: skip empty token octets
#pragma unroll
            for (int j = 0; j < 8; ++j) {
              const int t = oct * 8 + j;
              const float4 xv = *(const float4*)&xs[kg][t][dd4 * 4];  // broadcast
              acc[t].x += xv.x * w[dd4 * 4 + 0].x + xv.y * w[dd4 * 4 + 1].x +
                          xv.z * w[dd4 * 4 + 2].x + xv.w * w[dd4 * 4 + 3].x;
              acc[t].y += xv.x * w[dd4 * 4 + 0].y + xv.y * w[dd4 * 4 + 1].y +
                          xv.z * w[dd4 * 4 + 2].y + xv.w * w[dd4 * 4 + 3].y;
            }
          }
        }
      }
    }

    // ---- LDS reduce across k-groups + bias + tanh + store (4 rounds x 8 tokens) ----
    const int tt_r = tid >> 5;  // token-in-round 0..7
    const int ct_r = tid & 31;
#pragma unroll
    for (int r = 0; r < TG / 8; ++r) {
#pragma unroll
      for (int tt = 0; tt < 8; ++tt)
        red[kg][ct][tt] = acc[r * 8 + tt];
      __syncthreads();
      const int slot = r * 8 + tt_r;
      if (slot < T) {
        float2 s = make_float2(0.f, 0.f);
#pragma unroll
        for (int g = 0; g < KG; ++g) {
          const float2 p = red[g][ct_r][tt_r];
          s.x += p.x; s.y += p.y;
        }
        const int tok = toksL[beg + slot];
        const int u   = urls[tok];
        const float2 b = *(const float2*)&bias[(size_t)u * D_ + c0 + ct_r * 2];
        float2 o;
        o.x = tanhf(s.x + b.x);
        o.y = tanhf(s.y + b.y);
        *(float2*)&out[(size_t)tok * D_ + c0 + ct_r * 2] = o;
      }
      __syncthreads();  // red slots free before next round's writes
    }
  }
}

extern "C" void kernel_launch(void* const* d_in, const int* in_sizes, int n_in,
                              void* d_out, int out_size, void* d_ws, size_t ws_size,
                              hipStream_t stream) {
  const float* x     = (const float*)d_in[0];
  const int*   urls  = (const int*)d_in[1];
  const float* trans = (const float*)d_in[2];
  const float* bias  = (const float*)d_in[3];
  float* out = (float*)d_out;

  dim3 grid(CS, E_);
  fused_moe_kernel<<<grid, 256, 0, stream>>>(x, urls, trans, bias, out);
}